// Round 1
// baseline (104.770 us; speedup 1.0000x reference)
//
#include <hip/hip_runtime.h>

// Pointer-generator final distribution.
// out[b,t,v] = p_gen[b,t] * vocab[b,t,v]              for v <  V
//            = 0                                      for V <= v < Vext
// then out[b,t, ids[b,l]] += (1 - p_gen[b,t]) * attn[b,t,l]  (scatter-add)

// Kernel 1: scale vocab dist by p_gen, pad OOV slots with zeros.
// Grid: (ceil(Vext4/256), B*T). One block-row per output row -> no int div.
__global__ __launch_bounds__(256) void pgn_scale_pad_kernel(
    const float* __restrict__ vocab,   // [BT, V]
    const float* __restrict__ pg,      // [BT]
    float* __restrict__ out,           // [BT, Vext]
    int V4, int Vext4) {
  const int c4  = blockIdx.x * blockDim.x + threadIdx.x;   // float4 column
  const int row = blockIdx.y;
  if (c4 >= Vext4) return;

  float4 o;
  if (c4 < V4) {
    const float4 v =
        reinterpret_cast<const float4*>(vocab)[(long)row * V4 + c4];
    const float p = pg[row];   // uniform per block -> scalar load
    o = make_float4(v.x * p, v.y * p, v.z * p, v.w * p);
  } else {
    o = make_float4(0.f, 0.f, 0.f, 0.f);
  }
  reinterpret_cast<float4*>(out)[(long)row * Vext4 + c4] = o;
}

// Kernel 2: scatter-add copy probabilities.
// Grid: (T, B). One block per (b,t) row; threads stride over L.
__global__ __launch_bounds__(256) void pgn_scatter_kernel(
    const float* __restrict__ attn,    // [BT, L]
    const float* __restrict__ pg,      // [BT]
    const int* __restrict__ ids,       // [B, L]
    float* __restrict__ out,           // [BT, Vext]
    int T, int L, int Vext) {
  const int t = blockIdx.x;
  const int b = blockIdx.y;
  const int row = b * T + t;
  const float q = 1.0f - pg[row];
  float* __restrict__ orow = out + (long)row * Vext;
  const float* __restrict__ arow = attn + (long)row * L;
  const int* __restrict__ irow = ids + (long)b * L;

  for (int l = threadIdx.x; l < L; l += blockDim.x) {
    atomicAdd(orow + irow[l], q * arow[l]);
  }
}

extern "C" void kernel_launch(void* const* d_in, const int* in_sizes, int n_in,
                              void* d_out, int out_size, void* d_ws, size_t ws_size,
                              hipStream_t stream) {
  const float* vocab = (const float*)d_in[0];   // [B,T,V]
  const float* attn  = (const float*)d_in[1];   // [B,T,L]
  const float* pg    = (const float*)d_in[2];   // [B,T,1]
  const int*   ids   = (const int*)d_in[3];     // [B,L]
  // d_in[4] = batch_oov_len (scalar) — Vext derived from out_size instead.
  float* out = (float*)d_out;

  const int BT   = in_sizes[2];            // B*T
  const int V    = in_sizes[0] / BT;       // 50000
  const int L    = in_sizes[1] / BT;       // 400
  const int Vext = out_size / BT;          // 50100
  const int B    = in_sizes[3] / L;        // 16
  const int T    = BT / B;                 // 64

  const int V4 = V / 4, Vext4 = Vext / 4;  // both divisible (50000, 50100)

  dim3 grid1((Vext4 + 255) / 256, BT);
  pgn_scale_pad_kernel<<<grid1, 256, 0, stream>>>(vocab, pg, out, V4, Vext4);

  dim3 grid2(T, B);
  pgn_scatter_kernel<<<grid2, 256, 0, stream>>>(attn, pg, ids, out, T, L, Vext);
}

// Round 3
// 81.313 us; speedup vs baseline: 1.2885x; 1.2885x over previous
//
#include <hip/hip_runtime.h>

// Pointer-generator final distribution, fused single kernel.
// out[b,t,v] = p_gen[b,t] * vocab[b,t,v]        for v <  V
//            = 0                                for V <= v < Vext
// then out[b,t, ids[b,l]] += (1 - p_gen[b,t]) * attn[b,t,l]  (row-local
// scatter-add; duplicates accumulate, matching tf.scatter_nd semantics).
//
// One block per (b,t) row. The block streams+scales its whole row, then
// __syncthreads() (orders the block's own global writes for the block),
// then performs the row's 400 atomics. Scatter targets are row-local, so
// no cross-block ordering is ever needed.

typedef float float4v __attribute__((ext_vector_type(4)));  // clang vector:
// __builtin_nontemporal_load requires a true vector type, not HIP's struct.

__global__ __launch_bounds__(256) void pgn_fused_kernel(
    const float* __restrict__ vocab,   // [BT, V]
    const float* __restrict__ attn,    // [BT, L]
    const float* __restrict__ pg,      // [BT]
    const int* __restrict__ ids,       // [B, L]
    float* __restrict__ out,           // [BT, Vext]
    int T, int L, int V4, int Vext4) {
  const int row = blockIdx.x;          // 0..B*T-1
  const float p = pg[row];

  const float4v* __restrict__ vrow =
      reinterpret_cast<const float4v*>(vocab) + (long)row * V4;
  float4v* __restrict__ orow4 =
      reinterpret_cast<float4v*>(out) + (long)row * Vext4;

  // Stream + scale the row; zero-fill the OOV pad (must fully overwrite out
  // every call — harness does not re-poison between replays).
  for (int c = threadIdx.x; c < Vext4; c += 256) {
    float4v o;
    if (c < V4) {
      const float4v v = __builtin_nontemporal_load(vrow + c);  // streamed once
      o = v * p;
    } else {
      o = (float4v)(0.f);
    }
    orow4[c] = o;   // normal store: keep row lines in L2 for the atomics
  }

  __syncthreads();  // block's global writes visible to block

  const float q = 1.0f - p;
  const int b = row / T;  // scalar, once per block
  float* __restrict__ orow = out + (long)row * (Vext4 * 4);
  const float* __restrict__ arow = attn + (long)row * L;
  const int* __restrict__ irow = ids + (long)b * L;

  for (int l = threadIdx.x; l < L; l += 256) {
    atomicAdd(orow + irow[l], q * arow[l]);
  }
}

extern "C" void kernel_launch(void* const* d_in, const int* in_sizes, int n_in,
                              void* d_out, int out_size, void* d_ws, size_t ws_size,
                              hipStream_t stream) {
  const float* vocab = (const float*)d_in[0];   // [B,T,V]
  const float* attn  = (const float*)d_in[1];   // [B,T,L]
  const float* pg    = (const float*)d_in[2];   // [B,T,1]
  const int*   ids   = (const int*)d_in[3];     // [B,L]
  float* out = (float*)d_out;

  const int BT   = in_sizes[2];            // B*T = 1024
  const int V    = in_sizes[0] / BT;       // 50000
  const int L    = in_sizes[1] / BT;       // 400
  const int Vext = out_size / BT;          // 50100
  const int B    = in_sizes[3] / L;        // 16
  const int T    = BT / B;                 // 64

  const int V4 = V / 4, Vext4 = Vext / 4;  // 12500, 12525 (rows 16B-aligned)

  pgn_fused_kernel<<<BT, 256, 0, stream>>>(vocab, attn, pg, ids, out,
                                           T, L, V4, Vext4);
}